// Round 9
// baseline (159.785 us; speedup 1.0000x reference)
//
#include <hip/hip_runtime.h>
#include <hip/hip_bf16.h>
#include <cstdint>

// SelfSimilarity: out[b,i,j] = softmax_j( -T * max(||x_i - x_j||^2, 0) )
// bf16 MFMA via norm expansion; ||x||^2 from ROUNDED bf16 values so the
// diagonal logit is exactly 0 => max logit 0 => no online max needed.
//
// V8 = V7 + NONTEMPORAL full-line stores. Evidence: rocclr fillBuffer
// streams 512MiB at 6.5TB/s with FETCH~0 and WRITE=1.0x, while our plain
// full-line stores (V6/V7) showed FETCH~0.8x + WRITE=2.5x at 2.4TB/s:
// write-allocate + L2 thrash (64 resident blocks/XCD x 128KB window
// >> 4MB L2). V4's "NT is bad" result was confounded: NT was only tested
// on scattered sub-line instructions (RMW). NT + >=512B-contiguous
// per-instruction (this kernel's epilogue) should stream like fill.
// Keeps V7 structure: single sweep, P in regs, swapped MFMA, direct-L2
// B loads, XCD batch pinning, LDS-transposed full-line epilogue.

using bf16x8 = __attribute__((ext_vector_type(8))) short;
using f32x4  = __attribute__((ext_vector_type(4))) float;

#define TEMP   (1.0f / 13.544f)
#define LOG2E  1.4426950408889634f

// ---------------------------------------------------------------------------
// prep: fp32 -> bf16 (RNE) in MFMA-staging layout + csq[row] = -T*log2e*||x_bf||^2
// ws bf16 layout: [b][group=row>>4][qblock=k>>3][r=row&15][8 elems]
//   -> uint4 index: (b*128+g)*256 + q*16 + r
// ---------------------------------------------------------------------------
__global__ __launch_bounds__(256) void prep_kernel(
    const float* __restrict__ x, uint4* __restrict__ xbf, float* __restrict__ csq)
{
    const int t   = threadIdx.x;
    const int lr  = t >> 4;            // local row 0..15
    const int q   = t & 15;            // k-block of 8
    const int row = blockIdx.x * 16 + lr;   // 0..16383

    const float* xp = x + (size_t)row * 128 + q * 8;
    float4 a0 = *(const float4*)(xp);
    float4 a1 = *(const float4*)(xp + 4);
    float v[8] = {a0.x, a0.y, a0.z, a0.w, a1.x, a1.y, a1.z, a1.w};

    unsigned u[8];
    float s = 0.f;
#pragma unroll
    for (int e = 0; e < 8; ++e) {
        unsigned ui = __float_as_uint(v[e]);
        unsigned r  = (ui + 0x7FFFu + ((ui >> 16) & 1u)) >> 16;   // RNE to bf16
        u[e] = r;
        float d = __uint_as_float(r << 16);                        // decoded value
        s += d * d;                                                // norm of ROUNDED vec
    }
    uint4 pack;
    pack.x = u[0] | (u[1] << 16);
    pack.y = u[2] | (u[3] << 16);
    pack.z = u[4] | (u[5] << 16);
    pack.w = u[6] | (u[7] << 16);

    const int b  = row >> 11;
    const int g  = (row >> 4) & 127;
    const int rr = row & 15;
    xbf[(b * 128 + g) * 256 + q * 16 + rr] = pack;

#pragma unroll
    for (int m = 1; m < 16; m <<= 1) s += __shfl_xor(s, m, 64);
    if (q == 0) csq[row] = s * (-TEMP * LOG2E);
}

// ---------------------------------------------------------------------------
// main: per workgroup, M=16 rows x all 2048 cols, ONE sweep.
// 4 waves split each 128-col j-tile (wave w -> cols w*32..w*32+31).
// Swapped MFMA: acc[n][r] = out[i0 + l15][jt*128 + w*32 + n*16 + quad*4 + r]
// -> lane-local row, 4 consecutive cols per fragment. P kept in registers
// (16 tiles x 2 x f32x4 = 128 fp32/lane), sums inline; after the inv
// reduction, a 4-round LDS-transposed epilogue emits full-128B-line NT
// stores (2 rows x 512B contiguous per wave instruction).
// logit2 = log2e*(-T*dist) = C2L*dot + csq_i + csq_j, clamped <= 0.
// ---------------------------------------------------------------------------
__global__ __launch_bounds__(256, 2) void sim_kernel(
    const uint4* __restrict__ xbf, const float* __restrict__ csq, float* __restrict__ out)
{
    const int blk  = blockIdx.x;
    const int b    = blk & 7;             // batch pinned to XCD (round-robin dispatch)
    const int i0   = (blk >> 3) * 16;     // 128 row-tiles per batch
    const int tid  = threadIdx.x;
    const int w    = tid >> 6;
    const int lane = tid & 63;
    const int quad = lane >> 4;
    const int l15  = lane & 15;

    __shared__ __align__(16) char lsP[4][8192];   // epilogue: 4 x (16x128 f32 tile)
    __shared__ float lsSum[4][16];
    __shared__ __align__(16) float lsInv[16];

    const uint4* xbb  = xbf + (size_t)b * (128 * 256);
    const float* csqb = csq + b * 2048;

    // A fragments (i-rows): lane holds row i0+l15, k-chunk k4*4+quad.
    bf16x8 afrag[4];
#pragma unroll
    for (int k4 = 0; k4 < 4; ++k4) {
        uint4 vv = xbb[(i0 >> 4) * 256 + (k4 * 4 + quad) * 16 + l15];
        afrag[k4] = __builtin_bit_cast(bf16x8, vv);
    }

    const float csqi = csqb[i0 + l15];    // i is lane-local after the swap
    const float C2L  = 2.0f * TEMP * LOG2E;
    const int   c0   = w * 32;

    // ---- single sweep: P into registers, row sums inline ------------------
    f32x4 P0[16], P1[16];
    float sum_ = 0.f;
#pragma unroll
    for (int jt = 0; jt < 16; ++jt) {
        const int j0 = jt * 128;
        float4 cj0 = *(const float4*)(csqb + j0 + c0 + quad * 4);
        float4 cj1 = *(const float4*)(csqb + j0 + c0 + 16 + quad * 4);

        // B fragments direct from L2: 64 lanes x 16B contiguous per wave-op.
        const uint4* b0p = xbb + (size_t)(jt * 8 + w * 2 + 0) * 256 + quad * 16 + l15;
        const uint4* b1p = b0p + 256;

        f32x4 acc[2] = {};
#pragma unroll
        for (int k4 = 0; k4 < 4; ++k4) {
            bf16x8 b0 = __builtin_bit_cast(bf16x8, b0p[k4 * 64]);
            bf16x8 b1 = __builtin_bit_cast(bf16x8, b1p[k4 * 64]);
            // swapped operands: lane = i-row, regs = 4 consecutive j
            acc[0] = __builtin_amdgcn_mfma_f32_16x16x32_bf16(b0, afrag[k4], acc[0], 0, 0, 0);
            acc[1] = __builtin_amdgcn_mfma_f32_16x16x32_bf16(b1, afrag[k4], acc[1], 0, 0, 0);
        }

        f32x4 p0, p1;
        p0[0] = exp2f(fminf(fmaf(C2L, acc[0][0], csqi + cj0.x), 0.f));
        p0[1] = exp2f(fminf(fmaf(C2L, acc[0][1], csqi + cj0.y), 0.f));
        p0[2] = exp2f(fminf(fmaf(C2L, acc[0][2], csqi + cj0.z), 0.f));
        p0[3] = exp2f(fminf(fmaf(C2L, acc[0][3], csqi + cj0.w), 0.f));
        p1[0] = exp2f(fminf(fmaf(C2L, acc[1][0], csqi + cj1.x), 0.f));
        p1[1] = exp2f(fminf(fmaf(C2L, acc[1][1], csqi + cj1.y), 0.f));
        p1[2] = exp2f(fminf(fmaf(C2L, acc[1][2], csqi + cj1.z), 0.f));
        p1[3] = exp2f(fminf(fmaf(C2L, acc[1][3], csqi + cj1.w), 0.f));
        P0[jt] = p0;
        P1[jt] = p1;
        sum_ += p0[0] + p0[1] + p0[2] + p0[3] + p1[0] + p1[1] + p1[2] + p1[3];
    }

    // ---- reduce: across quads (lane bits 4,5), then across waves ----------
    sum_ += __shfl_xor(sum_, 16, 64);
    sum_ += __shfl_xor(sum_, 32, 64);
    if (quad == 0) lsSum[w][l15] = sum_;
    __syncthreads();
    if (tid < 16) {
        lsInv[tid] = 1.0f / (lsSum[0][tid] + lsSum[1][tid] + lsSum[2][tid] + lsSum[3][tid]);
    }
    __syncthreads();
    const float inv = lsInv[l15];

    // ---- epilogue: 4 rounds x (LDS-transpose 4 tiles, full-line NT store) -
    // LDS write: row l15 (512B stride), 16B slots XOR-swizzled by row&7
    // (verified in V6: correct + 0 bank conflicts). Read-back flat: per
    // wave-op 2 rows x 512B contiguous -> every 128B line written by ONE
    // global instruction; NT bypasses L2 write-allocate (fill-kernel mode).
    const int rowA = tid >> 5;                // 0..7
    const int rowB = rowA + 8;
    const int cb   = (tid & 31) << 4;         // byte offset within 512B row
    const int rswz = (rowA & 7) << 4;         // rowB&7 == rowA&7 -> same swizzle
    const int wr   = l15 << 9;                // l15 * 512
    const int ws   = (l15 & 7) << 4;
    const int wc0  = (c0 << 2) + (quad << 4); // byte col of p0
    float* obase = out + ((size_t)b * 2048 + i0) * 2048;

#pragma unroll
    for (int rd = 0; rd < 4; ++rd) {
#pragma unroll
        for (int t4 = 0; t4 < 4; ++t4) {
            const int jt = rd * 4 + t4;
            char* buf = lsP[t4];
            f32x4 s0 = P0[jt] * inv;
            f32x4 s1 = P1[jt] * inv;
            *(f32x4*)(buf + wr + ((wc0)      ^ ws)) = s0;
            *(f32x4*)(buf + wr + ((wc0 + 64) ^ ws)) = s1;
        }
        __syncthreads();
#pragma unroll
        for (int t4 = 0; t4 < 4; ++t4) {
            const int jt = rd * 4 + t4;
            const int j0 = jt * 128;
            char* buf = lsP[t4];
            f32x4 vA = *(const f32x4*)(buf + (rowA << 9) + (cb ^ rswz));
            f32x4 vB = *(const f32x4*)(buf + (rowB << 9) + (cb ^ rswz));
            __builtin_nontemporal_store(vA, (f32x4*)(obase + (size_t)rowA * 2048 + j0 + (tid & 31) * 4));
            __builtin_nontemporal_store(vB, (f32x4*)(obase + (size_t)rowB * 2048 + j0 + (tid & 31) * 4));
        }
        __syncthreads();   // before next round overwrites lsP
    }
}

extern "C" void kernel_launch(void* const* d_in, const int* in_sizes, int n_in,
                              void* d_out, int out_size, void* d_ws, size_t ws_size,
                              hipStream_t stream) {
    const float* x   = (const float*)d_in[0];
    float*       out = (float*)d_out;
    // ws: [0, 4MB) packed bf16 x; [4MB, 4MB+64KB) csq. Needs ~4.26 MB of ws.
    uint4* xbf = (uint4*)d_ws;
    float* csq = (float*)((char*)d_ws + (size_t)4 * 1024 * 1024);

    prep_kernel<<<1024, 256, 0, stream>>>(x, xbf, csq);     // 16384 rows
    sim_kernel<<<1024, 256, 0, stream>>>(xbf, csq, out);    // 8 batches x 128 row-tiles
}

// Round 10
// 156.662 us; speedup vs baseline: 1.0199x; 1.0199x over previous
//
#include <hip/hip_runtime.h>
#include <hip/hip_bf16.h>
#include <cstdint>

// SelfSimilarity: out[b,i,j] = softmax_j( -T * max(||x_i - x_j||^2, 0) )
// bf16 MFMA via norm expansion; ||x||^2 from ROUNDED bf16 values so the
// diagonal logit is exactly 0 => max logit 0 => no online max needed.
//
// V9 = V7 with the epilogue store GEOMETRY matched to fillBuffer's (the
// only pattern measured at 1.0x WRITE + ~0 FETCH + 6.5TB/s): every global
// store instruction writes 1KB contiguous within ONE row, and each wave's
// successive stores walk memory sequentially (wave w owns rows 4w..4w+3).
// V7's epilogue wrote 2x512B disjoint segments per instruction, jumping
// rows -- suspected to defeat EA write-combining (sub-line writebacks ->
// WRITE=2.5x, FETCH=0.8x, the remaining 45us of sim time). Plain stores
// (V7 beat V8's NT). Everything else identical to V7: single sweep, P in
// regs, swapped MFMA, direct-L2 B loads, XCD batch pinning, LDS swizzle.

using bf16x8 = __attribute__((ext_vector_type(8))) short;
using f32x4  = __attribute__((ext_vector_type(4))) float;

#define TEMP   (1.0f / 13.544f)
#define LOG2E  1.4426950408889634f

// ---------------------------------------------------------------------------
// prep: fp32 -> bf16 (RNE) in MFMA-staging layout + csq[row] = -T*log2e*||x_bf||^2
// ws bf16 layout: [b][group=row>>4][qblock=k>>3][r=row&15][8 elems]
//   -> uint4 index: (b*128+g)*256 + q*16 + r
// ---------------------------------------------------------------------------
__global__ __launch_bounds__(256) void prep_kernel(
    const float* __restrict__ x, uint4* __restrict__ xbf, float* __restrict__ csq)
{
    const int t   = threadIdx.x;
    const int lr  = t >> 4;            // local row 0..15
    const int q   = t & 15;            // k-block of 8
    const int row = blockIdx.x * 16 + lr;   // 0..16383

    const float* xp = x + (size_t)row * 128 + q * 8;
    float4 a0 = *(const float4*)(xp);
    float4 a1 = *(const float4*)(xp + 4);
    float v[8] = {a0.x, a0.y, a0.z, a0.w, a1.x, a1.y, a1.z, a1.w};

    unsigned u[8];
    float s = 0.f;
#pragma unroll
    for (int e = 0; e < 8; ++e) {
        unsigned ui = __float_as_uint(v[e]);
        unsigned r  = (ui + 0x7FFFu + ((ui >> 16) & 1u)) >> 16;   // RNE to bf16
        u[e] = r;
        float d = __uint_as_float(r << 16);                        // decoded value
        s += d * d;                                                // norm of ROUNDED vec
    }
    uint4 pack;
    pack.x = u[0] | (u[1] << 16);
    pack.y = u[2] | (u[3] << 16);
    pack.z = u[4] | (u[5] << 16);
    pack.w = u[6] | (u[7] << 16);

    const int b  = row >> 11;
    const int g  = (row >> 4) & 127;
    const int rr = row & 15;
    xbf[(b * 128 + g) * 256 + q * 16 + rr] = pack;

#pragma unroll
    for (int m = 1; m < 16; m <<= 1) s += __shfl_xor(s, m, 64);
    if (q == 0) csq[row] = s * (-TEMP * LOG2E);
}

// ---------------------------------------------------------------------------
// main: per workgroup, M=16 rows x all 2048 cols, ONE sweep.
// 4 waves split each 128-col j-tile (wave w -> cols w*32..w*32+31).
// Swapped MFMA: acc[n][r] = out[i0 + l15][jt*128 + w*32 + n*16 + quad*4 + r]
// -> lane-local row, 4 consecutive cols per fragment. P kept in registers
// (16 tiles x 2 x f32x4 = 128 fp32/lane), sums inline; after the inv
// reduction, a 4-round LDS-transposed epilogue emits 1KB-contiguous
// single-row store instructions, sequential per wave.
// logit2 = log2e*(-T*dist) = C2L*dot + csq_i + csq_j, clamped <= 0.
// ---------------------------------------------------------------------------
__global__ __launch_bounds__(256, 2) void sim_kernel(
    const uint4* __restrict__ xbf, const float* __restrict__ csq, float* __restrict__ out)
{
    const int blk  = blockIdx.x;
    const int b    = blk & 7;             // batch pinned to XCD (round-robin dispatch)
    const int i0   = (blk >> 3) * 16;     // 128 row-tiles per batch
    const int tid  = threadIdx.x;
    const int w    = tid >> 6;
    const int lane = tid & 63;
    const int quad = lane >> 4;
    const int l15  = lane & 15;

    __shared__ __align__(16) char lsP[4][8192];   // epilogue: 4 x (16x128 f32 tile)
    __shared__ float lsSum[4][16];
    __shared__ __align__(16) float lsInv[16];

    const uint4* xbb  = xbf + (size_t)b * (128 * 256);
    const float* csqb = csq + b * 2048;

    // A fragments (i-rows): lane holds row i0+l15, k-chunk k4*4+quad.
    bf16x8 afrag[4];
#pragma unroll
    for (int k4 = 0; k4 < 4; ++k4) {
        uint4 vv = xbb[(i0 >> 4) * 256 + (k4 * 4 + quad) * 16 + l15];
        afrag[k4] = __builtin_bit_cast(bf16x8, vv);
    }

    const float csqi = csqb[i0 + l15];    // i is lane-local after the swap
    const float C2L  = 2.0f * TEMP * LOG2E;
    const int   c0   = w * 32;

    // ---- single sweep: P into registers, row sums inline ------------------
    f32x4 P0[16], P1[16];
    float sum_ = 0.f;
#pragma unroll
    for (int jt = 0; jt < 16; ++jt) {
        const int j0 = jt * 128;
        float4 cj0 = *(const float4*)(csqb + j0 + c0 + quad * 4);
        float4 cj1 = *(const float4*)(csqb + j0 + c0 + 16 + quad * 4);

        // B fragments direct from L2: 64 lanes x 16B contiguous per wave-op.
        const uint4* b0p = xbb + (size_t)(jt * 8 + w * 2 + 0) * 256 + quad * 16 + l15;
        const uint4* b1p = b0p + 256;

        f32x4 acc[2] = {};
#pragma unroll
        for (int k4 = 0; k4 < 4; ++k4) {
            bf16x8 b0 = __builtin_bit_cast(bf16x8, b0p[k4 * 64]);
            bf16x8 b1 = __builtin_bit_cast(bf16x8, b1p[k4 * 64]);
            // swapped operands: lane = i-row, regs = 4 consecutive j
            acc[0] = __builtin_amdgcn_mfma_f32_16x16x32_bf16(b0, afrag[k4], acc[0], 0, 0, 0);
            acc[1] = __builtin_amdgcn_mfma_f32_16x16x32_bf16(b1, afrag[k4], acc[1], 0, 0, 0);
        }

        f32x4 p0, p1;
        p0[0] = exp2f(fminf(fmaf(C2L, acc[0][0], csqi + cj0.x), 0.f));
        p0[1] = exp2f(fminf(fmaf(C2L, acc[0][1], csqi + cj0.y), 0.f));
        p0[2] = exp2f(fminf(fmaf(C2L, acc[0][2], csqi + cj0.z), 0.f));
        p0[3] = exp2f(fminf(fmaf(C2L, acc[0][3], csqi + cj0.w), 0.f));
        p1[0] = exp2f(fminf(fmaf(C2L, acc[1][0], csqi + cj1.x), 0.f));
        p1[1] = exp2f(fminf(fmaf(C2L, acc[1][1], csqi + cj1.y), 0.f));
        p1[2] = exp2f(fminf(fmaf(C2L, acc[1][2], csqi + cj1.z), 0.f));
        p1[3] = exp2f(fminf(fmaf(C2L, acc[1][3], csqi + cj1.w), 0.f));
        P0[jt] = p0;
        P1[jt] = p1;
        sum_ += p0[0] + p0[1] + p0[2] + p0[3] + p1[0] + p1[1] + p1[2] + p1[3];
    }

    // ---- reduce: across quads (lane bits 4,5), then across waves ----------
    sum_ += __shfl_xor(sum_, 16, 64);
    sum_ += __shfl_xor(sum_, 32, 64);
    if (quad == 0) lsSum[w][l15] = sum_;
    __syncthreads();
    if (tid < 16) {
        lsInv[tid] = 1.0f / (lsSum[0][tid] + lsSum[1][tid] + lsSum[2][tid] + lsSum[3][tid]);
    }
    __syncthreads();
    const float inv = lsInv[l15];

    // ---- epilogue: 4 rounds x (LDS-transpose 4 tiles, fill-style store) ---
    // LDS write: unchanged from V7 (verified correct, 0 bank conflicts).
    // Read/store remap: wave w owns rows 4w..4w+3. Round rd covers byte
    // cols [rd*2048, rd*2048+2048) of each row; per row it issues two 1KB
    // single-row contiguous wave-instructions (seg=0,1), walking memory
    // sequentially. Source tile t4 = seg*2 + (lane>>5); within-tile byte
    // c32 = (lane&31)*16, same XOR swizzle per row.
    const int wr   = l15 << 9;                // l15 * 512
    const int ws   = (l15 & 7) << 4;
    const int wc0  = (c0 << 2) + (quad << 4); // byte col of p0
    const int c32  = (lane & 31) << 4;        // byte within 512B half
    const int half = lane >> 5;               // 0 or 1
    char* obase = (char*)(out + ((size_t)b * 2048 + i0) * 2048);

#pragma unroll
    for (int rd = 0; rd < 4; ++rd) {
#pragma unroll
        for (int t4 = 0; t4 < 4; ++t4) {
            const int jt = rd * 4 + t4;
            char* buf = lsP[t4];
            f32x4 s0 = P0[jt] * inv;
            f32x4 s1 = P1[jt] * inv;
            *(f32x4*)(buf + wr + ((wc0)      ^ ws)) = s0;
            *(f32x4*)(buf + wr + ((wc0 + 64) ^ ws)) = s1;
        }
        __syncthreads();
#pragma unroll
        for (int r4 = 0; r4 < 4; ++r4) {
            const int row = w * 4 + r4;
            const int swz = (row & 7) << 4;
#pragma unroll
            for (int seg = 0; seg < 2; ++seg) {
                const char* buf = lsP[seg * 2 + half];
                f32x4 v = *(const f32x4*)(buf + (row << 9) + (c32 ^ swz));
                *(f32x4*)(obase + (size_t)row * 8192 + rd * 2048 + seg * 1024 + (lane << 4)) = v;
            }
        }
        __syncthreads();   // before next round overwrites lsP
    }
}

extern "C" void kernel_launch(void* const* d_in, const int* in_sizes, int n_in,
                              void* d_out, int out_size, void* d_ws, size_t ws_size,
                              hipStream_t stream) {
    const float* x   = (const float*)d_in[0];
    float*       out = (float*)d_out;
    // ws: [0, 4MB) packed bf16 x; [4MB, 4MB+64KB) csq. Needs ~4.26 MB of ws.
    uint4* xbf = (uint4*)d_ws;
    float* csq = (float*)((char*)d_ws + (size_t)4 * 1024 * 1024);

    prep_kernel<<<1024, 256, 0, stream>>>(x, xbf, csq);     // 16384 rows
    sim_kernel<<<1024, 256, 0, stream>>>(xbf, csq, out);    // 8 batches x 128 row-tiles
}